// Round 1
// baseline (18566.376 us; speedup 1.0000x reference)
//
#include <hip/hip_runtime.h>
#include <cmath>

// Problem constants
static constexpr int Bb  = 4;
static constexpr int S   = 2048;
static constexpr int DIN = 4096;
static constexpr int P   = 512;    // D_PROJ == D_MEM
static constexpr int AST = 512;    // assistant_start
static constexpr int TR  = 1536;   // run length
static constexpr int NWG = 64;     // scan workgroups
#define DTC (1.0f/1535.0f)

// Workspace layout (float element offsets)
static constexpr size_t SZ      = (size_t)Bb * S * P;          // 4,194,304
static constexpr size_t GXSZ    = (size_t)TR * Bb * P;         // 3,145,728
static constexpr size_t OFF_Q   = 0;
static constexpr size_t OFF_K   = SZ;
static constexpr size_t OFF_V   = 2 * SZ;
static constexpr size_t OFF_GXZ = 0;                           // reuses Q/K/V after attention
static constexpr size_t OFF_GXR = GXSZ;
static constexpr size_t OFF_GXH = 2 * GXSZ;
static constexpr size_t OFF_HH  = 3 * GXSZ;                    // h_hist: (TR+1) x 4 x 512
static constexpr size_t OFF_FEAT= 3 * GXSZ + (size_t)(TR + 1) * Bb * P; // 12,584,960
static constexpr size_t OFF_SC  = OFF_FEAT + SZ;               // scores/attn, reused as rh_hist
static constexpr size_t OFF_RH  = OFF_SC;
static constexpr size_t OFF_CTR = OFF_SC + (size_t)Bb * S * S; // sync counters (ints)

#define INNER16 \
  acc[0][0] += af.x*bf.x; acc[0][1] += af.x*bf.y; acc[0][2] += af.x*bf.z; acc[0][3] += af.x*bf.w; \
  acc[1][0] += af.y*bf.x; acc[1][1] += af.y*bf.y; acc[1][2] += af.y*bf.z; acc[1][3] += af.y*bf.w; \
  acc[2][0] += af.z*bf.x; acc[2][1] += af.z*bf.y; acc[2][2] += af.z*bf.z; acc[2][3] += af.z*bf.w; \
  acc[3][0] += af.w*bf.x; acc[3][1] += af.w*bf.y; acc[3][2] += af.w*bf.z; acc[3][3] += af.w*bf.w;

__global__ __launch_bounds__(256) void k_zero(float* p, int n) {
  int i = blockIdx.x * 256 + threadIdx.x;
  if (i < n) p[i] = 0.f;
}

// ---------------- QKV projection: (8192 x 4096) @ (4096 x 512) + bias, z selects Q/K/V
__global__ __launch_bounds__(256) void k_qkv(
    const float* __restrict__ x,
    const float* __restrict__ W0, const float* __restrict__ W1, const float* __restrict__ W2,
    const float* __restrict__ b0, const float* __restrict__ b1, const float* __restrict__ b2,
    float* __restrict__ O0, float* __restrict__ O1, float* __restrict__ O2)
{
  __shared__ float As[32][68];  // transposed A tile: As[k][m]
  __shared__ float Bs[32][64];
  const int z = blockIdx.z;
  const float* W    = (z == 0) ? W0 : (z == 1) ? W1 : W2;
  const float* bias = (z == 0) ? b0 : (z == 1) ? b1 : b2;
  float* Out        = (z == 0) ? O0 : (z == 1) ? O1 : O2;
  const int tid = threadIdx.x;
  const int m0 = blockIdx.y * 64, n0 = blockIdx.x * 64;
  const int tm = tid >> 4, tn = tid & 15;
  const int la_m = tid >> 3;
  const int la_k = (tid & 7) << 2;
  const int lb_k = tid >> 4;
  const int lb_n = (tid & 15) << 2;
  float acc[4][4] = {};
  for (int k0 = 0; k0 < DIN; k0 += 32) {
#pragma unroll
    for (int pp = 0; pp < 2; ++pp) {
      int m = la_m + pp * 32;
      float4 v = *(const float4*)(x + (size_t)(m0 + m) * DIN + k0 + la_k);
      As[la_k + 0][m] = v.x; As[la_k + 1][m] = v.y; As[la_k + 2][m] = v.z; As[la_k + 3][m] = v.w;
    }
#pragma unroll
    for (int pp = 0; pp < 2; ++pp) {
      int k = lb_k + pp * 16;
      *(float4*)&Bs[k][lb_n] = *(const float4*)(W + (size_t)(k0 + k) * P + n0 + lb_n);
    }
    __syncthreads();
#pragma unroll
    for (int kk = 0; kk < 32; ++kk) {
      float4 af = *(float4*)&As[kk][tm << 2];
      float4 bf = *(float4*)&Bs[kk][tn << 2];
      INNER16
    }
    __syncthreads();
  }
  float4 bv = *(const float4*)(bias + n0 + (tn << 2));
#pragma unroll
  for (int i = 0; i < 4; ++i) {
    int row = m0 + (tm << 2) + i;
    float4 o = make_float4(acc[i][0] + bv.x, acc[i][1] + bv.y, acc[i][2] + bv.z, acc[i][3] + bv.w);
    *(float4*)(Out + (size_t)row * P + n0 + (tn << 2)) = o;
  }
}

// ---------------- scores = Q @ K^T / scale, causal mask (only tiles jt <= qt computed)
__global__ __launch_bounds__(256) void k_scores(
    const float* __restrict__ Q, const float* __restrict__ Km, float* __restrict__ Sc)
{
  const int jt = blockIdx.x, qt = blockIdx.y, b = blockIdx.z;
  if (jt > qt) return;
  __shared__ float As[32][68];  // Q^T: As[k][i]
  __shared__ float Bs[32][68];  // K^T: Bs[k][j]
  const float* Qb = Q + (size_t)b * S * P;
  const float* Kb = Km + (size_t)b * S * P;
  const int tid = threadIdx.x;
  const int i0 = qt * 64, j0 = jt * 64;
  const int tm = tid >> 4, tn = tid & 15;
  const int lr = tid >> 3;
  const int lk = (tid & 7) << 2;
  float acc[4][4] = {};
  for (int k0 = 0; k0 < P; k0 += 32) {
#pragma unroll
    for (int pp = 0; pp < 2; ++pp) {
      int r = lr + pp * 32;
      float4 v = *(const float4*)(Qb + (size_t)(i0 + r) * P + k0 + lk);
      As[lk + 0][r] = v.x; As[lk + 1][r] = v.y; As[lk + 2][r] = v.z; As[lk + 3][r] = v.w;
      float4 w = *(const float4*)(Kb + (size_t)(j0 + r) * P + k0 + lk);
      Bs[lk + 0][r] = w.x; Bs[lk + 1][r] = w.y; Bs[lk + 2][r] = w.z; Bs[lk + 3][r] = w.w;
    }
    __syncthreads();
#pragma unroll
    for (int kk = 0; kk < 32; ++kk) {
      float4 af = *(float4*)&As[kk][tm << 2];
      float4 bf = *(float4*)&Bs[kk][tn << 2];
      INNER16
    }
    __syncthreads();
  }
  const float invs = 0.04419417382f;  // 1/sqrt(512+1e-6)
#pragma unroll
  for (int i = 0; i < 4; ++i) {
    int ig = i0 + (tm << 2) + i;
    float v0 = acc[i][0] * invs, v1 = acc[i][1] * invs, v2 = acc[i][2] * invs, v3 = acc[i][3] * invs;
    int jg = j0 + (tn << 2);
    if (jg + 0 > ig) v0 = -1e9f;
    if (jg + 1 > ig) v1 = -1e9f;
    if (jg + 2 > ig) v2 = -1e9f;
    if (jg + 3 > ig) v3 = -1e9f;
    *(float4*)(Sc + (size_t)b * S * S + (size_t)ig * S + jg) = make_float4(v0, v1, v2, v3);
  }
}

// ---------------- row softmax over [0, i], zero-fill to end of diagonal tile (in place)
__global__ __launch_bounds__(256) void k_softmax(float* __restrict__ Sc)
{
  const int i = blockIdx.x, b = blockIdx.y;
  float* row = Sc + (size_t)b * S * S + (size_t)i * S;
  __shared__ float sv[2048];
  __shared__ float red[256];
  const int tid = threadIdx.x;
  const int len = i + 1;
  float lmax = -1e30f;
  for (int k = tid; k < len; k += 256) { float v = row[k]; sv[k] = v; lmax = fmaxf(lmax, v); }
  red[tid] = lmax; __syncthreads();
  for (int s = 128; s > 0; s >>= 1) { if (tid < s) red[tid] = fmaxf(red[tid], red[tid + s]); __syncthreads(); }
  const float m = red[0]; __syncthreads();
  float lsum = 0.f;
  for (int k = tid; k < len; k += 256) { float e = expf(sv[k] - m); sv[k] = e; lsum += e; }
  red[tid] = lsum; __syncthreads();
  for (int s = 128; s > 0; s >>= 1) { if (tid < s) red[tid] += red[tid + s]; __syncthreads(); }
  const float inv = 1.0f / red[0];
  for (int k = tid; k < len; k += 256) row[k] = sv[k] * inv;
  const int tail = ((i >> 6) + 1) << 6;
  for (int k = len + tid; k < tail; k += 256) row[k] = 0.f;
}

// ---------------- feat = attn @ V (skip upper-triangle tiles)
__global__ __launch_bounds__(256) void k_attnv(
    const float* __restrict__ At, const float* __restrict__ V, float* __restrict__ F)
{
  __shared__ float As[32][68];
  __shared__ float Bs[32][64];
  const int qt = blockIdx.y, b = blockIdx.z;
  const float* Ab = At + (size_t)b * S * S;
  const float* Vb = V + (size_t)b * S * P;
  const int tid = threadIdx.x;
  const int m0 = qt * 64, n0 = blockIdx.x * 64;
  const int tm = tid >> 4, tn = tid & 15;
  const int la_m = tid >> 3;
  const int la_k = (tid & 7) << 2;
  const int lb_k = tid >> 4;
  const int lb_n = (tid & 15) << 2;
  float acc[4][4] = {};
  const int kext = (qt + 1) * 64;
  for (int k0 = 0; k0 < kext; k0 += 32) {
#pragma unroll
    for (int pp = 0; pp < 2; ++pp) {
      int m = la_m + pp * 32;
      float4 v = *(const float4*)(Ab + (size_t)(m0 + m) * S + k0 + la_k);
      As[la_k + 0][m] = v.x; As[la_k + 1][m] = v.y; As[la_k + 2][m] = v.z; As[la_k + 3][m] = v.w;
    }
#pragma unroll
    for (int pp = 0; pp < 2; ++pp) {
      int k = lb_k + pp * 16;
      *(float4*)&Bs[k][lb_n] = *(const float4*)(Vb + (size_t)(k0 + k) * P + n0 + lb_n);
    }
    __syncthreads();
#pragma unroll
    for (int kk = 0; kk < 32; ++kk) {
      float4 af = *(float4*)&As[kk][tm << 2];
      float4 bf = *(float4*)&Bs[kk][tn << 2];
      INNER16
    }
    __syncthreads();
  }
#pragma unroll
  for (int i = 0; i < 4; ++i) {
    int row = m0 + (tm << 2) + i;
    *(float4*)(F + (size_t)b * S * P + (size_t)row * P + n0 + (tn << 2)) =
        make_float4(acc[i][0], acc[i][1], acc[i][2], acc[i][3]);
  }
}

// ---------------- gx = feat_assist @ {Wz,Wr,Wh} + bias; output layout [t][b][j]
__global__ __launch_bounds__(256) void k_gx(
    const float* __restrict__ feat,
    const float* __restrict__ Wz, const float* __restrict__ Wr, const float* __restrict__ Wh,
    const float* __restrict__ bz, const float* __restrict__ br, const float* __restrict__ bh,
    float* __restrict__ gz, float* __restrict__ gr, float* __restrict__ gh)
{
  __shared__ float As[32][68];
  __shared__ float Bs[32][64];
  const int z = blockIdx.z;
  const float* W    = (z == 0) ? Wz : (z == 1) ? Wr : Wh;
  const float* bias = (z == 0) ? bz : (z == 1) ? br : bh;
  float* Out        = (z == 0) ? gz : (z == 1) ? gr : gh;
  const int tid = threadIdx.x;
  const int m0 = blockIdx.y * 64, n0 = blockIdx.x * 64;
  const int bb = m0 / TR;
  const int t0 = m0 - bb * TR;
  const float* Arow = feat + ((size_t)(bb * S + AST + t0)) * P;  // 64 consecutive rows
  const int tm = tid >> 4, tn = tid & 15;
  const int la_m = tid >> 3;
  const int la_k = (tid & 7) << 2;
  const int lb_k = tid >> 4;
  const int lb_n = (tid & 15) << 2;
  float acc[4][4] = {};
  for (int k0 = 0; k0 < P; k0 += 32) {
#pragma unroll
    for (int pp = 0; pp < 2; ++pp) {
      int m = la_m + pp * 32;
      float4 v = *(const float4*)(Arow + (size_t)m * P + k0 + la_k);
      As[la_k + 0][m] = v.x; As[la_k + 1][m] = v.y; As[la_k + 2][m] = v.z; As[la_k + 3][m] = v.w;
    }
#pragma unroll
    for (int pp = 0; pp < 2; ++pp) {
      int k = lb_k + pp * 16;
      *(float4*)&Bs[k][lb_n] = *(const float4*)(W + (size_t)(k0 + k) * P + n0 + lb_n);
    }
    __syncthreads();
#pragma unroll
    for (int kk = 0; kk < 32; ++kk) {
      float4 af = *(float4*)&As[kk][tm << 2];
      float4 bf = *(float4*)&Bs[kk][tn << 2];
      INNER16
    }
    __syncthreads();
  }
  float4 bv = *(const float4*)(bias + n0 + (tn << 2));
#pragma unroll
  for (int i = 0; i < 4; ++i) {
    int t = t0 + (tm << 2) + i;
    float4 o = make_float4(acc[i][0] + bv.x, acc[i][1] + bv.y, acc[i][2] + bv.z, acc[i][3] + bv.w);
    *(float4*)(Out + ((size_t)t * 4 + bb) * P + n0 + (tn << 2)) = o;
  }
}

// ---------------- attention pooling over prefix + h0; writes h_hist slot 0
__global__ __launch_bounds__(256) void k_pool(
    const float* __restrict__ feat, const float* __restrict__ Wscore,
    const float* __restrict__ Wp2h, const float* __restrict__ bp2h,
    float* __restrict__ hh)
{
  const int b = blockIdx.x;
  const float* fb = feat + (size_t)b * S * P;  // prefix rows 0..511
  __shared__ float sw[512];
  __shared__ float pool[512];
  __shared__ float red[256];
  const int tid = threadIdx.x;
  for (int u = tid; u < 512; u += 256) {
    float s = 0.f;
    for (int p4 = 0; p4 < P; p4 += 4) {
      float4 f = *(const float4*)(fb + (size_t)u * P + p4);
      float4 w = *(const float4*)(Wscore + p4);
      s += f.x * w.x + f.y * w.y + f.z * w.z + f.w * w.w;
    }
    sw[u] = s;
  }
  __syncthreads();
  float lm = fmaxf(sw[tid], sw[tid + 256]);
  red[tid] = lm; __syncthreads();
  for (int s = 128; s > 0; s >>= 1) { if (tid < s) red[tid] = fmaxf(red[tid], red[tid + s]); __syncthreads(); }
  const float m = red[0]; __syncthreads();
  float e0 = expf(sw[tid] - m), e1 = expf(sw[tid + 256] - m);
  sw[tid] = e0; sw[tid + 256] = e1;
  red[tid] = e0 + e1; __syncthreads();
  for (int s = 128; s > 0; s >>= 1) { if (tid < s) red[tid] += red[tid + s]; __syncthreads(); }
  const float inv = 1.0f / red[0];
  __syncthreads();
  sw[tid] *= inv; sw[tid + 256] *= inv;
  __syncthreads();
  for (int p = tid; p < P; p += 256) {
    float a = 0.f;
    for (int u = 0; u < 512; ++u) a += sw[u] * fb[(size_t)u * P + p];
    pool[p] = a;
  }
  __syncthreads();
  for (int j = tid; j < P; j += 256) {
    float a = bp2h[j];
    for (int p = 0; p < P; ++p) a += pool[p] * Wp2h[(size_t)p * P + j];
    hh[(size_t)b * P + j] = tanhf(a);  // t=0 slot: (0*4+b)*512+j
  }
}

// ---------------- persistent GRU scan: 64 WGs, 8 U-columns each, flag-sync per phase
__global__ __launch_bounds__(256) void k_scan(
    const float* __restrict__ Uz, const float* __restrict__ Ur, const float* __restrict__ Uh,
    const float* __restrict__ gz, const float* __restrict__ gr, const float* __restrict__ gh,
    const float* __restrict__ Wmem, const float* __restrict__ bmem,
    float* __restrict__ hh, float* __restrict__ rhb,
    int* __restrict__ ctrA, int* __restrict__ ctrB,
    float* __restrict__ out)
{
  __shared__ float Us[3][8][520];
  __shared__ float hb[4][516];
  __shared__ float red[256][4];
  __shared__ float zloc[4][8];
  __shared__ float hploc[4][8];
  const int g = blockIdx.x;
  const int tid = threadIdx.x;
  const int j0 = g * 8;

  for (int idx = tid; idx < 3 * 512 * 8; idx += 256) {
    int mt = idx >> 12;
    int rem = idx & 4095;
    int i = rem >> 3, c = rem & 7;
    const float* U = (mt == 0) ? Uz : (mt == 1) ? Ur : Uh;
    Us[mt][c][i] = U[(size_t)i * P + j0 + c];
  }
  float wmv = 0.f;
  if (tid < 32) wmv = Wmem[j0 + (tid >> 2)];
  const float bmv = bmem[0];

  const int gate = tid >> 7;
  const int cA = (tid >> 4) & 7;
  const int ipA = tid & 15;
  const int cB = tid >> 5;
  const int ipB = tid & 31;
  __syncthreads();

  for (int t = 0; t < TR; ++t) {
    // load full h(t) into LDS
    {
      const float* src = hh + (size_t)t * 4 * P;
      for (int idx = tid; idx < 512; idx += 256) {
        int b = idx >> 7, i4 = (idx & 127) << 2;
        *(float4*)&hb[b][i4] = *(const float4*)(src + b * P + i4);
      }
    }
    float gxa = 0.f;
    if (tid < 64) {
      int gg = tid >> 5, c = (tid >> 2) & 7, b = tid & 3;
      const float* gp = gg ? gr : gz;
      gxa = gp[((size_t)t * 4 + b) * P + j0 + c];
    }
    __syncthreads();
    // phase A: h @ {Uz,Ur} for own columns
    float a0 = 0.f, a1 = 0.f, a2 = 0.f, a3 = 0.f;
    {
      const float* Uc = &Us[gate][cA][0];
#pragma unroll
      for (int n = 0; n < 8; ++n) {
        int off = ((n << 4) | ipA) << 2;
        float4 u = *(const float4*)&Uc[off];
        float4 h0v = *(const float4*)&hb[0][off];
        float4 h1v = *(const float4*)&hb[1][off];
        float4 h2v = *(const float4*)&hb[2][off];
        float4 h3v = *(const float4*)&hb[3][off];
        a0 += u.x * h0v.x + u.y * h0v.y + u.z * h0v.z + u.w * h0v.w;
        a1 += u.x * h1v.x + u.y * h1v.y + u.z * h1v.z + u.w * h1v.w;
        a2 += u.x * h2v.x + u.y * h2v.y + u.z * h2v.z + u.w * h2v.w;
        a3 += u.x * h3v.x + u.y * h3v.y + u.z * h3v.z + u.w * h3v.w;
      }
    }
    *(float4*)&red[tid][0] = make_float4(a0, a1, a2, a3);
    __syncthreads();
    if (tid < 64) {
      int gg = tid >> 5, c = (tid >> 2) & 7, b = tid & 3;
      float s = 0.f;
      int base = (gg << 7) | (c << 4);
#pragma unroll
      for (int q = 0; q < 16; ++q) s += red[base | q][b];
      float a = gxa + s;
      float sg = 1.0f / (1.0f + expf(-a));
      if (gg == 0) {
        zloc[b][c] = sg;
      } else {
        float hov = hb[b][j0 + c];
        hploc[b][c] = hov;
        rhb[((size_t)t * 4 + b) * P + j0 + c] = sg * hov;
      }
    }
    __syncthreads();
    if (tid == 0) {
      __threadfence();
      atomicAdd(ctrA + t, 1);
      while (__hip_atomic_load(ctrA + t, __ATOMIC_RELAXED, __HIP_MEMORY_SCOPE_AGENT) < NWG)
        __builtin_amdgcn_s_sleep(1);
      __threadfence();
    }
    __syncthreads();
    // load full rh(t)
    {
      const float* src = rhb + (size_t)t * 4 * P;
      for (int idx = tid; idx < 512; idx += 256) {
        int b = idx >> 7, i4 = (idx & 127) << 2;
        *(float4*)&hb[b][i4] = *(const float4*)(src + b * P + i4);
      }
    }
    float gxhv = 0.f;
    if (tid < 32) {
      int c = tid >> 2, b = tid & 3;
      gxhv = gh[((size_t)t * 4 + b) * P + j0 + c];
    }
    __syncthreads();
    // phase B: rh @ Uh for own columns
    float p0 = 0.f, p1 = 0.f, p2 = 0.f, p3 = 0.f;
    {
      const float* Uc = &Us[2][cB][0];
#pragma unroll
      for (int n = 0; n < 4; ++n) {
        int off = ((n << 5) | ipB) << 2;
        float4 u = *(const float4*)&Uc[off];
        float4 h0v = *(const float4*)&hb[0][off];
        float4 h1v = *(const float4*)&hb[1][off];
        float4 h2v = *(const float4*)&hb[2][off];
        float4 h3v = *(const float4*)&hb[3][off];
        p0 += u.x * h0v.x + u.y * h0v.y + u.z * h0v.z + u.w * h0v.w;
        p1 += u.x * h1v.x + u.y * h1v.y + u.z * h1v.z + u.w * h1v.w;
        p2 += u.x * h2v.x + u.y * h2v.y + u.z * h2v.z + u.w * h2v.w;
        p3 += u.x * h3v.x + u.y * h3v.y + u.z * h3v.z + u.w * h3v.w;
      }
    }
    *(float4*)&red[tid][0] = make_float4(p0, p1, p2, p3);
    __syncthreads();
    if (tid < 32) {
      int c = tid >> 2, b = tid & 3;
      float s = 0.f;
      int base = c << 5;
#pragma unroll
      for (int q = 0; q < 32; ++q) s += red[base | q][b];
      float hhat = tanhf(gxhv + s);
      float z = zloc[b][c], hp = hploc[b][c];
      float hn = (1.0f - z) * hp + z * hhat;
      float dt = (t == 0) ? 0.f : DTC;
      float ho = hn + dt * (hn - hp);
      hh[((size_t)(t + 1) * 4 + b) * P + j0 + c] = ho;
      float pl = ho * wmv;
      pl += __shfl_xor(pl, 4);
      pl += __shfl_xor(pl, 8);
      pl += __shfl_xor(pl, 16);
      if (c == 0) {
        if (g == 0) pl += bmv;
        atomicAdd(out + (size_t)b * TR + t, pl);
      }
    }
    __syncthreads();
    if (tid == 0) {
      __threadfence();
      atomicAdd(ctrB + t, 1);
      while (__hip_atomic_load(ctrB + t, __ATOMIC_RELAXED, __HIP_MEMORY_SCOPE_AGENT) < NWG)
        __builtin_amdgcn_s_sleep(1);
      __threadfence();
    }
    __syncthreads();
  }
}

extern "C" void kernel_launch(void* const* d_in, const int* in_sizes, int n_in,
                              void* d_out, int out_size, void* d_ws, size_t ws_size,
                              hipStream_t stream)
{
  const float* x      = (const float*)d_in[0];
  const float* Wq     = (const float*)d_in[1];
  const float* bq     = (const float*)d_in[2];
  const float* Wk     = (const float*)d_in[3];
  const float* bk     = (const float*)d_in[4];
  const float* Wv     = (const float*)d_in[5];
  const float* bv     = (const float*)d_in[6];
  const float* Wz     = (const float*)d_in[7];
  const float* Uz     = (const float*)d_in[8];
  const float* bz     = (const float*)d_in[9];
  const float* Wr     = (const float*)d_in[10];
  const float* Ur     = (const float*)d_in[11];
  const float* br     = (const float*)d_in[12];
  const float* Wh     = (const float*)d_in[13];
  const float* Uh     = (const float*)d_in[14];
  const float* bh     = (const float*)d_in[15];
  const float* Wmem   = (const float*)d_in[16];
  const float* bmem   = (const float*)d_in[17];
  const float* Wp2h   = (const float*)d_in[18];
  const float* bp2h   = (const float*)d_in[19];
  const float* Wscore = (const float*)d_in[20];

  float* ws  = (float*)d_ws;
  float* out = (float*)d_out;
  float* Q    = ws + OFF_Q;
  float* Kk   = ws + OFF_K;
  float* V    = ws + OFF_V;
  float* feat = ws + OFF_FEAT;
  float* Sc   = ws + OFF_SC;
  float* gz   = ws + OFF_GXZ;
  float* gr   = ws + OFF_GXR;
  float* gh   = ws + OFF_GXH;
  float* hhist= ws + OFF_HH;
  float* rh   = ws + OFF_RH;
  int*   ctrA = (int*)(ws + OFF_CTR);
  int*   ctrB = ctrA + TR;

  k_zero<<<dim3(24), 256, 0, stream>>>(out, Bb * TR);
  k_zero<<<dim3(12), 256, 0, stream>>>((float*)ctrA, 2 * TR);

  k_qkv<<<dim3(8, 128, 3), 256, 0, stream>>>(x, Wq, Wk, Wv, bq, bk, bv, Q, Kk, V);
  k_scores<<<dim3(32, 32, 4), 256, 0, stream>>>(Q, Kk, Sc);
  k_softmax<<<dim3(2048, 4), 256, 0, stream>>>(Sc);
  k_attnv<<<dim3(8, 32, 4), 256, 0, stream>>>(Sc, V, feat);
  k_gx<<<dim3(8, 96, 3), 256, 0, stream>>>(feat, Wz, Wr, Wh, bz, br, bh, gz, gr, gh);
  k_pool<<<dim3(4), 256, 0, stream>>>(feat, Wscore, Wp2h, bp2h, hhist);
  k_scan<<<dim3(NWG), 256, 0, stream>>>(Uz, Ur, Uh, gz, gr, gh, Wmem, bmem,
                                        hhist, rh, ctrA, ctrB, out);
}

// Round 2
// 16000.766 us; speedup vs baseline: 1.1603x; 1.1603x over previous
//
#include <hip/hip_runtime.h>
#include <cmath>

// Problem constants
static constexpr int Bb  = 4;
static constexpr int S   = 2048;
static constexpr int DIN = 4096;
static constexpr int P   = 512;    // D_PROJ == D_MEM
static constexpr int AST = 512;    // assistant_start
static constexpr int TR  = 1536;   // run length
static constexpr int NWG = 32;     // scan workgroups (16 U-columns each)
#define DTC (1.0f/1535.0f)

// Workspace layout (float element offsets)
static constexpr size_t SZ      = (size_t)Bb * S * P;          // 4,194,304
static constexpr size_t GXSZ    = (size_t)TR * Bb * P;         // 3,145,728
static constexpr size_t OFF_Q   = 0;
static constexpr size_t OFF_K   = SZ;
static constexpr size_t OFF_V   = 2 * SZ;
static constexpr size_t OFF_GXZ = 0;                           // reuses Q/K/V after attention
static constexpr size_t OFF_GXR = GXSZ;
static constexpr size_t OFF_GXH = 2 * GXSZ;
static constexpr size_t OFF_HH  = 3 * GXSZ;                    // h_hist: (TR+1) x 4 x 512
static constexpr size_t OFF_FEAT= 3 * GXSZ + (size_t)(TR + 1) * Bb * P; // 12,584,960
static constexpr size_t OFF_SC  = OFF_FEAT + SZ;               // scores/attn, reused as rh_hist
static constexpr size_t OFF_RH  = OFF_SC;
static constexpr size_t OFF_CTR = OFF_SC + (size_t)Bb * S * S; // sync counters (ints)

#define INNER16 \
  acc[0][0] += af.x*bf.x; acc[0][1] += af.x*bf.y; acc[0][2] += af.x*bf.z; acc[0][3] += af.x*bf.w; \
  acc[1][0] += af.y*bf.x; acc[1][1] += af.y*bf.y; acc[1][2] += af.y*bf.z; acc[1][3] += af.y*bf.w; \
  acc[2][0] += af.z*bf.x; acc[2][1] += af.z*bf.y; acc[2][2] += af.z*bf.z; acc[2][3] += af.z*bf.w; \
  acc[3][0] += af.w*bf.x; acc[3][1] += af.w*bf.y; acc[3][2] += af.w*bf.z; acc[3][3] += af.w*bf.w;

__global__ __launch_bounds__(256) void k_zero(float* p, int n) {
  int i = blockIdx.x * 256 + threadIdx.x;
  if (i < n) p[i] = 0.f;
}

// ---------------- QKV projection: (8192 x 4096) @ (4096 x 512) + bias, z selects Q/K/V
__global__ __launch_bounds__(256) void k_qkv(
    const float* __restrict__ x,
    const float* __restrict__ W0, const float* __restrict__ W1, const float* __restrict__ W2,
    const float* __restrict__ b0, const float* __restrict__ b1, const float* __restrict__ b2,
    float* __restrict__ O0, float* __restrict__ O1, float* __restrict__ O2)
{
  __shared__ float As[32][68];  // transposed A tile: As[k][m]
  __shared__ float Bs[32][64];
  const int z = blockIdx.z;
  const float* W    = (z == 0) ? W0 : (z == 1) ? W1 : W2;
  const float* bias = (z == 0) ? b0 : (z == 1) ? b1 : b2;
  float* Out        = (z == 0) ? O0 : (z == 1) ? O1 : O2;
  const int tid = threadIdx.x;
  const int m0 = blockIdx.y * 64, n0 = blockIdx.x * 64;
  const int tm = tid >> 4, tn = tid & 15;
  const int la_m = tid >> 3;
  const int la_k = (tid & 7) << 2;
  const int lb_k = tid >> 4;
  const int lb_n = (tid & 15) << 2;
  float acc[4][4] = {};
  for (int k0 = 0; k0 < DIN; k0 += 32) {
#pragma unroll
    for (int pp = 0; pp < 2; ++pp) {
      int m = la_m + pp * 32;
      float4 v = *(const float4*)(x + (size_t)(m0 + m) * DIN + k0 + la_k);
      As[la_k + 0][m] = v.x; As[la_k + 1][m] = v.y; As[la_k + 2][m] = v.z; As[la_k + 3][m] = v.w;
    }
#pragma unroll
    for (int pp = 0; pp < 2; ++pp) {
      int k = lb_k + pp * 16;
      *(float4*)&Bs[k][lb_n] = *(const float4*)(W + (size_t)(k0 + k) * P + n0 + lb_n);
    }
    __syncthreads();
#pragma unroll
    for (int kk = 0; kk < 32; ++kk) {
      float4 af = *(float4*)&As[kk][tm << 2];
      float4 bf = *(float4*)&Bs[kk][tn << 2];
      INNER16
    }
    __syncthreads();
  }
  float4 bv = *(const float4*)(bias + n0 + (tn << 2));
#pragma unroll
  for (int i = 0; i < 4; ++i) {
    int row = m0 + (tm << 2) + i;
    float4 o = make_float4(acc[i][0] + bv.x, acc[i][1] + bv.y, acc[i][2] + bv.z, acc[i][3] + bv.w);
    *(float4*)(Out + (size_t)row * P + n0 + (tn << 2)) = o;
  }
}

// ---------------- scores = Q @ K^T / scale, causal mask (only tiles jt <= qt computed)
__global__ __launch_bounds__(256) void k_scores(
    const float* __restrict__ Q, const float* __restrict__ Km, float* __restrict__ Sc)
{
  const int jt = blockIdx.x, qt = blockIdx.y, b = blockIdx.z;
  if (jt > qt) return;
  __shared__ float As[32][68];  // Q^T: As[k][i]
  __shared__ float Bs[32][68];  // K^T: Bs[k][j]
  const float* Qb = Q + (size_t)b * S * P;
  const float* Kb = Km + (size_t)b * S * P;
  const int tid = threadIdx.x;
  const int i0 = qt * 64, j0 = jt * 64;
  const int tm = tid >> 4, tn = tid & 15;
  const int lr = tid >> 3;
  const int lk = (tid & 7) << 2;
  float acc[4][4] = {};
  for (int k0 = 0; k0 < P; k0 += 32) {
#pragma unroll
    for (int pp = 0; pp < 2; ++pp) {
      int r = lr + pp * 32;
      float4 v = *(const float4*)(Qb + (size_t)(i0 + r) * P + k0 + lk);
      As[lk + 0][r] = v.x; As[lk + 1][r] = v.y; As[lk + 2][r] = v.z; As[lk + 3][r] = v.w;
      float4 w = *(const float4*)(Kb + (size_t)(j0 + r) * P + k0 + lk);
      Bs[lk + 0][r] = w.x; Bs[lk + 1][r] = w.y; Bs[lk + 2][r] = w.z; Bs[lk + 3][r] = w.w;
    }
    __syncthreads();
#pragma unroll
    for (int kk = 0; kk < 32; ++kk) {
      float4 af = *(float4*)&As[kk][tm << 2];
      float4 bf = *(float4*)&Bs[kk][tn << 2];
      INNER16
    }
    __syncthreads();
  }
  const float invs = 0.04419417382f;  // 1/sqrt(512+1e-6)
#pragma unroll
  for (int i = 0; i < 4; ++i) {
    int ig = i0 + (tm << 2) + i;
    float v0 = acc[i][0] * invs, v1 = acc[i][1] * invs, v2 = acc[i][2] * invs, v3 = acc[i][3] * invs;
    int jg = j0 + (tn << 2);
    if (jg + 0 > ig) v0 = -1e9f;
    if (jg + 1 > ig) v1 = -1e9f;
    if (jg + 2 > ig) v2 = -1e9f;
    if (jg + 3 > ig) v3 = -1e9f;
    *(float4*)(Sc + (size_t)b * S * S + (size_t)ig * S + jg) = make_float4(v0, v1, v2, v3);
  }
}

// ---------------- row softmax over [0, i], zero-fill to end of diagonal tile (in place)
__global__ __launch_bounds__(256) void k_softmax(float* __restrict__ Sc)
{
  const int i = blockIdx.x, b = blockIdx.y;
  float* row = Sc + (size_t)b * S * S + (size_t)i * S;
  __shared__ float sv[2048];
  __shared__ float red[256];
  const int tid = threadIdx.x;
  const int len = i + 1;
  float lmax = -1e30f;
  for (int k = tid; k < len; k += 256) { float v = row[k]; sv[k] = v; lmax = fmaxf(lmax, v); }
  red[tid] = lmax; __syncthreads();
  for (int s = 128; s > 0; s >>= 1) { if (tid < s) red[tid] = fmaxf(red[tid], red[tid + s]); __syncthreads(); }
  const float m = red[0]; __syncthreads();
  float lsum = 0.f;
  for (int k = tid; k < len; k += 256) { float e = expf(sv[k] - m); sv[k] = e; lsum += e; }
  red[tid] = lsum; __syncthreads();
  for (int s = 128; s > 0; s >>= 1) { if (tid < s) red[tid] += red[tid + s]; __syncthreads(); }
  const float inv = 1.0f / red[0];
  for (int k = tid; k < len; k += 256) row[k] = sv[k] * inv;
  const int tail = ((i >> 6) + 1) << 6;
  for (int k = len + tid; k < tail; k += 256) row[k] = 0.f;
}

// ---------------- feat = attn @ V (skip upper-triangle tiles)
__global__ __launch_bounds__(256) void k_attnv(
    const float* __restrict__ At, const float* __restrict__ V, float* __restrict__ F)
{
  __shared__ float As[32][68];
  __shared__ float Bs[32][64];
  const int qt = blockIdx.y, b = blockIdx.z;
  const float* Ab = At + (size_t)b * S * S;
  const float* Vb = V + (size_t)b * S * P;
  const int tid = threadIdx.x;
  const int m0 = qt * 64, n0 = blockIdx.x * 64;
  const int tm = tid >> 4, tn = tid & 15;
  const int la_m = tid >> 3;
  const int la_k = (tid & 7) << 2;
  const int lb_k = tid >> 4;
  const int lb_n = (tid & 15) << 2;
  float acc[4][4] = {};
  const int kext = (qt + 1) * 64;
  for (int k0 = 0; k0 < kext; k0 += 32) {
#pragma unroll
    for (int pp = 0; pp < 2; ++pp) {
      int m = la_m + pp * 32;
      float4 v = *(const float4*)(Ab + (size_t)(m0 + m) * S + k0 + la_k);
      As[la_k + 0][m] = v.x; As[la_k + 1][m] = v.y; As[la_k + 2][m] = v.z; As[la_k + 3][m] = v.w;
    }
#pragma unroll
    for (int pp = 0; pp < 2; ++pp) {
      int k = lb_k + pp * 16;
      *(float4*)&Bs[k][lb_n] = *(const float4*)(Vb + (size_t)(k0 + k) * P + n0 + lb_n);
    }
    __syncthreads();
#pragma unroll
    for (int kk = 0; kk < 32; ++kk) {
      float4 af = *(float4*)&As[kk][tm << 2];
      float4 bf = *(float4*)&Bs[kk][tn << 2];
      INNER16
    }
    __syncthreads();
  }
#pragma unroll
  for (int i = 0; i < 4; ++i) {
    int row = m0 + (tm << 2) + i;
    *(float4*)(F + (size_t)b * S * P + (size_t)row * P + n0 + (tn << 2)) =
        make_float4(acc[i][0], acc[i][1], acc[i][2], acc[i][3]);
  }
}

// ---------------- gx = feat_assist @ {Wz,Wr,Wh} + bias; output layout [t][b][j]
__global__ __launch_bounds__(256) void k_gx(
    const float* __restrict__ feat,
    const float* __restrict__ Wz, const float* __restrict__ Wr, const float* __restrict__ Wh,
    const float* __restrict__ bz, const float* __restrict__ br, const float* __restrict__ bh,
    float* __restrict__ gz, float* __restrict__ gr, float* __restrict__ gh)
{
  __shared__ float As[32][68];
  __shared__ float Bs[32][64];
  const int z = blockIdx.z;
  const float* W    = (z == 0) ? Wz : (z == 1) ? Wr : Wh;
  const float* bias = (z == 0) ? bz : (z == 1) ? br : bh;
  float* Out        = (z == 0) ? gz : (z == 1) ? gr : gh;
  const int tid = threadIdx.x;
  const int m0 = blockIdx.y * 64, n0 = blockIdx.x * 64;
  const int bb = m0 / TR;
  const int t0 = m0 - bb * TR;
  const float* Arow = feat + ((size_t)(bb * S + AST + t0)) * P;  // 64 consecutive rows
  const int tm = tid >> 4, tn = tid & 15;
  const int la_m = tid >> 3;
  const int la_k = (tid & 7) << 2;
  const int lb_k = tid >> 4;
  const int lb_n = (tid & 15) << 2;
  float acc[4][4] = {};
  for (int k0 = 0; k0 < P; k0 += 32) {
#pragma unroll
    for (int pp = 0; pp < 2; ++pp) {
      int m = la_m + pp * 32;
      float4 v = *(const float4*)(Arow + (size_t)m * P + k0 + la_k);
      As[la_k + 0][m] = v.x; As[la_k + 1][m] = v.y; As[la_k + 2][m] = v.z; As[la_k + 3][m] = v.w;
    }
#pragma unroll
    for (int pp = 0; pp < 2; ++pp) {
      int k = lb_k + pp * 16;
      *(float4*)&Bs[k][lb_n] = *(const float4*)(W + (size_t)(k0 + k) * P + n0 + lb_n);
    }
    __syncthreads();
#pragma unroll
    for (int kk = 0; kk < 32; ++kk) {
      float4 af = *(float4*)&As[kk][tm << 2];
      float4 bf = *(float4*)&Bs[kk][tn << 2];
      INNER16
    }
    __syncthreads();
  }
  float4 bv = *(const float4*)(bias + n0 + (tn << 2));
#pragma unroll
  for (int i = 0; i < 4; ++i) {
    int t = t0 + (tm << 2) + i;
    float4 o = make_float4(acc[i][0] + bv.x, acc[i][1] + bv.y, acc[i][2] + bv.z, acc[i][3] + bv.w);
    *(float4*)(Out + ((size_t)t * 4 + bb) * P + n0 + (tn << 2)) = o;
  }
}

// ---------------- attention pooling over prefix + h0; writes h_hist slot 0
__global__ __launch_bounds__(256) void k_pool(
    const float* __restrict__ feat, const float* __restrict__ Wscore,
    const float* __restrict__ Wp2h, const float* __restrict__ bp2h,
    float* __restrict__ hh)
{
  const int b = blockIdx.x;
  const float* fb = feat + (size_t)b * S * P;  // prefix rows 0..511
  __shared__ float sw[512];
  __shared__ float pool[512];
  __shared__ float red[256];
  const int tid = threadIdx.x;
  for (int u = tid; u < 512; u += 256) {
    float s = 0.f;
    for (int p4 = 0; p4 < P; p4 += 4) {
      float4 f = *(const float4*)(fb + (size_t)u * P + p4);
      float4 w = *(const float4*)(Wscore + p4);
      s += f.x * w.x + f.y * w.y + f.z * w.z + f.w * w.w;
    }
    sw[u] = s;
  }
  __syncthreads();
  float lm = fmaxf(sw[tid], sw[tid + 256]);
  red[tid] = lm; __syncthreads();
  for (int s = 128; s > 0; s >>= 1) { if (tid < s) red[tid] = fmaxf(red[tid], red[tid + s]); __syncthreads(); }
  const float m = red[0]; __syncthreads();
  float e0 = expf(sw[tid] - m), e1 = expf(sw[tid + 256] - m);
  sw[tid] = e0; sw[tid + 256] = e1;
  red[tid] = e0 + e1; __syncthreads();
  for (int s = 128; s > 0; s >>= 1) { if (tid < s) red[tid] += red[tid + s]; __syncthreads(); }
  const float inv = 1.0f / red[0];
  __syncthreads();
  sw[tid] *= inv; sw[tid + 256] *= inv;
  __syncthreads();
  for (int p = tid; p < P; p += 256) {
    float a = 0.f;
    for (int u = 0; u < 512; ++u) a += sw[u] * fb[(size_t)u * P + p];
    pool[p] = a;
  }
  __syncthreads();
  for (int j = tid; j < P; j += 256) {
    float a = bp2h[j];
    for (int p = 0; p < P; ++p) a += pool[p] * Wp2h[(size_t)p * P + j];
    hh[(size_t)b * P + j] = tanhf(a);  // t=0 slot: (0*4+b)*512+j
  }
}

// ---------------- persistent GRU scan: 32 WGs, 16 U-columns each.
// Cross-WG communication: relaxed AGENT-scope atomic stores (write-through to
// LLC, no L2 flush) + flag counters. NO __threadfence (avoids buffer_wbl2).
// Ordering: data stores -> __syncthreads (compiler drains vmcnt(0)) -> flag add.
__global__ __launch_bounds__(256) void k_scan(
    const float* __restrict__ Uz, const float* __restrict__ Ur, const float* __restrict__ Uh,
    const float* __restrict__ gz, const float* __restrict__ gr, const float* __restrict__ gh,
    const float* __restrict__ Wmem, const float* __restrict__ bmem,
    float* __restrict__ hh, float* __restrict__ rhb,
    int* __restrict__ ctrA, int* __restrict__ ctrB,
    float* __restrict__ out)
{
  __shared__ float Us[3][2][8][520];
  __shared__ float hb[4][516];
  __shared__ float red[256][4];
  __shared__ float zloc[2][4][8];
  __shared__ float hploc[2][4][8];
  const int g = blockIdx.x;
  const int tid = threadIdx.x;
  const int j0 = g * 16;

  for (int idx = tid; idx < 3 * 512 * 16; idx += 256) {
    int mt = idx >> 13;                // 8192 elements per matrix
    int rem = idx & 8191;
    int i = rem >> 4, c = rem & 15;
    const float* U = (mt == 0) ? Uz : (mt == 1) ? Ur : Uh;
    Us[mt][c >> 3][c & 7][i] = U[(size_t)i * P + j0 + c];
  }
  float wmv0 = 0.f, wmv1 = 0.f;
  if (tid < 32) { int c = (tid >> 2) & 7; wmv0 = Wmem[j0 + c]; wmv1 = Wmem[j0 + 8 + c]; }
  const float bmv = bmem[0];

  const int gate = tid >> 7;
  const int cA = (tid >> 4) & 7;
  const int ipA = tid & 15;
  const int cB = tid >> 5;
  const int ipB = tid & 31;
  __syncthreads();

  for (int t = 0; t < TR; ++t) {
    // broadcast-load h(t) from LLC into LDS
    {
      unsigned long long* src = (unsigned long long*)(hh + (size_t)t * 4 * P);
      for (int idx = tid; idx < 1024; idx += 256) {
        unsigned long long u = __hip_atomic_load(src + idx, __ATOMIC_RELAXED, __HIP_MEMORY_SCOPE_AGENT);
        union { unsigned long long uu; float f[2]; } cv; cv.uu = u;
        int b = idx >> 8, k2 = (idx & 255) << 1;
        hb[b][k2] = cv.f[0]; hb[b][k2 + 1] = cv.f[1];
      }
    }
    __syncthreads();
    // phase A: z,r for this WG's 16 columns (two 8-col groups)
    for (int sub = 0; sub < 2; ++sub) {
      float gxa = 0.f;
      if (tid < 64) {
        int gg = tid >> 5, c = (tid >> 2) & 7, b = tid & 3;
        const float* gp = gg ? gr : gz;
        gxa = gp[((size_t)t * 4 + b) * P + j0 + sub * 8 + c];
      }
      float a0 = 0.f, a1 = 0.f, a2 = 0.f, a3 = 0.f;
      {
        const float* Uc = &Us[gate][sub][cA][0];
#pragma unroll
        for (int n = 0; n < 8; ++n) {
          int off = ((n << 4) | ipA) << 2;
          float4 u = *(const float4*)&Uc[off];
          float4 h0v = *(const float4*)&hb[0][off];
          float4 h1v = *(const float4*)&hb[1][off];
          float4 h2v = *(const float4*)&hb[2][off];
          float4 h3v = *(const float4*)&hb[3][off];
          a0 += u.x * h0v.x + u.y * h0v.y + u.z * h0v.z + u.w * h0v.w;
          a1 += u.x * h1v.x + u.y * h1v.y + u.z * h1v.z + u.w * h1v.w;
          a2 += u.x * h2v.x + u.y * h2v.y + u.z * h2v.z + u.w * h2v.w;
          a3 += u.x * h3v.x + u.y * h3v.y + u.z * h3v.z + u.w * h3v.w;
        }
      }
      *(float4*)&red[tid][0] = make_float4(a0, a1, a2, a3);
      __syncthreads();
      if (tid < 64) {
        int gg = tid >> 5, c = (tid >> 2) & 7, b = tid & 3;
        float s = 0.f;
        int base = (gg << 7) | (c << 4);
#pragma unroll
        for (int q = 0; q < 16; ++q) s += red[base | q][b];
        float a = gxa + s;
        float sg = 1.0f / (1.0f + expf(-a));
        if (gg == 0) {
          zloc[sub][b][c] = sg;
        } else {
          float hov = hb[b][j0 + sub * 8 + c];
          hploc[sub][b][c] = hov;
          __hip_atomic_store(rhb + ((size_t)t * 4 + b) * P + j0 + sub * 8 + c, sg * hov,
                             __ATOMIC_RELAXED, __HIP_MEMORY_SCOPE_AGENT);
        }
      }
      __syncthreads();
    }
    if (tid == 0) {
      __hip_atomic_fetch_add(ctrA + t, 1, __ATOMIC_RELAXED, __HIP_MEMORY_SCOPE_AGENT);
      while (__hip_atomic_load(ctrA + t, __ATOMIC_RELAXED, __HIP_MEMORY_SCOPE_AGENT) < NWG) {}
    }
    __syncthreads();
    // broadcast-load rh(t)
    {
      unsigned long long* src = (unsigned long long*)(rhb + (size_t)t * 4 * P);
      for (int idx = tid; idx < 1024; idx += 256) {
        unsigned long long u = __hip_atomic_load(src + idx, __ATOMIC_RELAXED, __HIP_MEMORY_SCOPE_AGENT);
        union { unsigned long long uu; float f[2]; } cv; cv.uu = u;
        int b = idx >> 8, k2 = (idx & 255) << 1;
        hb[b][k2] = cv.f[0]; hb[b][k2 + 1] = cv.f[1];
      }
    }
    __syncthreads();
    // phase B: h_hat, h_new, h_out; publish h(t+1); accumulate logit partial
    float plsum = 0.f;
    for (int sub = 0; sub < 2; ++sub) {
      float gxhv = 0.f;
      if (tid < 32) {
        int c = (tid >> 2) & 7, b = tid & 3;
        gxhv = gh[((size_t)t * 4 + b) * P + j0 + sub * 8 + c];
      }
      float p0 = 0.f, p1 = 0.f, p2 = 0.f, p3 = 0.f;
      {
        const float* Uc = &Us[2][sub][cB][0];
#pragma unroll
        for (int n = 0; n < 4; ++n) {
          int off = ((n << 5) | ipB) << 2;
          float4 u = *(const float4*)&Uc[off];
          float4 h0v = *(const float4*)&hb[0][off];
          float4 h1v = *(const float4*)&hb[1][off];
          float4 h2v = *(const float4*)&hb[2][off];
          float4 h3v = *(const float4*)&hb[3][off];
          p0 += u.x * h0v.x + u.y * h0v.y + u.z * h0v.z + u.w * h0v.w;
          p1 += u.x * h1v.x + u.y * h1v.y + u.z * h1v.z + u.w * h1v.w;
          p2 += u.x * h2v.x + u.y * h2v.y + u.z * h2v.z + u.w * h2v.w;
          p3 += u.x * h3v.x + u.y * h3v.y + u.z * h3v.z + u.w * h3v.w;
        }
      }
      *(float4*)&red[tid][0] = make_float4(p0, p1, p2, p3);
      __syncthreads();
      if (tid < 32) {
        int c = (tid >> 2) & 7, b = tid & 3;
        float s = 0.f;
        int base = c << 5;
#pragma unroll
        for (int q = 0; q < 32; ++q) s += red[base | q][b];
        float hhat = tanhf(gxhv + s);
        float z = zloc[sub][b][c], hp = hploc[sub][b][c];
        float hn = (1.0f - z) * hp + z * hhat;
        float dtv = (t == 0) ? 0.f : DTC;
        float ho = hn + dtv * (hn - hp);
        __hip_atomic_store(hh + ((size_t)(t + 1) * 4 + b) * P + j0 + sub * 8 + c, ho,
                           __ATOMIC_RELAXED, __HIP_MEMORY_SCOPE_AGENT);
        plsum += ho * (sub ? wmv1 : wmv0);
      }
      __syncthreads();
    }
    if (tid == 0) {
      __hip_atomic_fetch_add(ctrB + t, 1, __ATOMIC_RELAXED, __HIP_MEMORY_SCOPE_AGENT);
      while (__hip_atomic_load(ctrB + t, __ATOMIC_RELAXED, __HIP_MEMORY_SCOPE_AGENT) < NWG) {}
    }
    __syncthreads();
    // logit write for step t — issued after the barrier so it overlaps the
    // next step's h broadcast
    if (tid < 32) {
      float pl = plsum;
      pl += __shfl_xor(pl, 4);
      pl += __shfl_xor(pl, 8);
      pl += __shfl_xor(pl, 16);
      int c = (tid >> 2) & 7, b = tid & 3;
      if (c == 0) {
        if (g == 0) pl += bmv;
        atomicAdd(out + (size_t)b * TR + t, pl);
      }
    }
  }
}

extern "C" void kernel_launch(void* const* d_in, const int* in_sizes, int n_in,
                              void* d_out, int out_size, void* d_ws, size_t ws_size,
                              hipStream_t stream)
{
  const float* x      = (const float*)d_in[0];
  const float* Wq     = (const float*)d_in[1];
  const float* bq     = (const float*)d_in[2];
  const float* Wk     = (const float*)d_in[3];
  const float* bk     = (const float*)d_in[4];
  const float* Wv     = (const float*)d_in[5];
  const float* bv     = (const float*)d_in[6];
  const float* Wz     = (const float*)d_in[7];
  const float* Uz     = (const float*)d_in[8];
  const float* bz     = (const float*)d_in[9];
  const float* Wr     = (const float*)d_in[10];
  const float* Ur     = (const float*)d_in[11];
  const float* br     = (const float*)d_in[12];
  const float* Wh     = (const float*)d_in[13];
  const float* Uh     = (const float*)d_in[14];
  const float* bh     = (const float*)d_in[15];
  const float* Wmem   = (const float*)d_in[16];
  const float* bmem   = (const float*)d_in[17];
  const float* Wp2h   = (const float*)d_in[18];
  const float* bp2h   = (const float*)d_in[19];
  const float* Wscore = (const float*)d_in[20];

  float* ws  = (float*)d_ws;
  float* out = (float*)d_out;
  float* Q    = ws + OFF_Q;
  float* Kk   = ws + OFF_K;
  float* V    = ws + OFF_V;
  float* feat = ws + OFF_FEAT;
  float* Sc   = ws + OFF_SC;
  float* gz   = ws + OFF_GXZ;
  float* gr   = ws + OFF_GXR;
  float* gh   = ws + OFF_GXH;
  float* hhist= ws + OFF_HH;
  float* rh   = ws + OFF_RH;
  int*   ctrA = (int*)(ws + OFF_CTR);
  int*   ctrB = ctrA + TR;

  k_zero<<<dim3(24), 256, 0, stream>>>(out, Bb * TR);
  k_zero<<<dim3(12), 256, 0, stream>>>((float*)ctrA, 2 * TR);

  k_qkv<<<dim3(8, 128, 3), 256, 0, stream>>>(x, Wq, Wk, Wv, bq, bk, bv, Q, Kk, V);
  k_scores<<<dim3(32, 32, 4), 256, 0, stream>>>(Q, Kk, Sc);
  k_softmax<<<dim3(2048, 4), 256, 0, stream>>>(Sc);
  k_attnv<<<dim3(8, 32, 4), 256, 0, stream>>>(Sc, V, feat);
  k_gx<<<dim3(8, 96, 3), 256, 0, stream>>>(feat, Wz, Wr, Wh, bz, br, bh, gz, gr, gh);
  k_pool<<<dim3(4), 256, 0, stream>>>(feat, Wscore, Wp2h, bp2h, hhist);
  k_scan<<<dim3(NWG), 256, 0, stream>>>(Uz, Ur, Uh, gz, gr, gh, Wmem, bmem,
                                        hhist, rh, ctrA, ctrB, out);
}